// Round 5
// baseline (195.424 us; speedup 1.0000x reference)
//
#include <hip/hip_runtime.h>
#include <hip/hip_bf16.h>
#include <stdint.h>

typedef float f32x4 __attribute__((ext_vector_type(4)));
typedef __bf16 bf16x8 __attribute__((ext_vector_type(8)));

#define NBH 64      // B*H
#define SS 1024     // SQ == SKV
#define DAUG 160    // augmented head dim 132 padded to 160
#define KAPPA 0.18033688011104293f  // 0.125 * log2(e), folded into Q~

static __device__ __forceinline__ unsigned short f2b(float f) {
  union { float f; uint32_t u; } v; v.f = f;
  return (unsigned short)((v.u + 0x7fffu + ((v.u >> 16) & 1u)) >> 16);
}
static __device__ __forceinline__ float b2f(unsigned short s) {
  union { uint32_t u; float f; } v; v.u = ((uint32_t)s) << 16;
  return v.f;
}

static __device__ __forceinline__ void async16(const void* g, void* l) {
  __builtin_amdgcn_global_load_lds(
      (const __attribute__((address_space(1))) uint32_t*)g,
      (__attribute__((address_space(3))) uint32_t*)l, 16, 0, 0);
}

// ---------------- f32 -> bf16 conversion for 7 tensors ----------------
__global__ void convert7(const float* q, const float* k, const float* v,
                         const float* wq, const float* wk, const float* wv, const float* wo,
                         unsigned short* xq, unsigned short* xk, unsigned short* xv,
                         unsigned short* bwq, unsigned short* bwk, unsigned short* bwv,
                         unsigned short* bwo) {
  const float* s; unsigned short* d; int n;
  switch (blockIdx.y) {
    case 0: s = q;  d = xq;  n = 4194304; break;
    case 1: s = k;  d = xk;  n = 4194304; break;
    case 2: s = v;  d = xv;  n = 4194304; break;
    case 3: s = wq; d = bwq; n = 1048576; break;
    case 4: s = wk; d = bwk; n = 1048576; break;
    case 5: s = wv; d = bwv; n = 1048576; break;
    default: s = wo; d = bwo; n = 1048576; break;
  }
  int n4 = n >> 2;
  for (int i = blockIdx.x * blockDim.x + threadIdx.x; i < n4; i += gridDim.x * blockDim.x) {
    float4 f = ((const float4*)s)[i];
    ushort4 o;
    o.x = f2b(f.x); o.y = f2b(f.y); o.z = f2b(f.z); o.w = f2b(f.w);
    ((ushort4*)d)[i] = o;
  }
}

// ---------------- QKV projection GEMM: Y = X @ W^T, 2-phase dbuf ----------------
// grid (32, 8, 3), block 256. BM=BN=128, BK=32. Q path scaled by KAPPA.
__global__ __launch_bounds__(256) void proj_qkv(
    const unsigned short* __restrict__ Xq, const unsigned short* __restrict__ Xk,
    const unsigned short* __restrict__ Xv, const unsigned short* __restrict__ Wqb,
    const unsigned short* __restrict__ Wkb, const unsigned short* __restrict__ Wvb,
    unsigned short* __restrict__ Qt, unsigned short* __restrict__ Kt,
    unsigned short* __restrict__ Vp) {
  const int z = blockIdx.z;
  const unsigned short* A = (z == 0) ? Xq : (z == 1) ? Xk : Xv;
  const unsigned short* Bw = (z == 0) ? Wqb : (z == 1) ? Wkb : Wvb;
  unsigned short* Dst = (z == 0) ? Qt : (z == 1) ? Kt : Vp;
  const int dstride = (z == 2) ? 64 : DAUG;
  const float sc = (z == 0) ? KAPPA : 1.0f;

  __shared__ unsigned short At[2][128 * 32];
  __shared__ unsigned short Bt[2][128 * 32];

  const int tid = threadIdx.x, wave = tid >> 6, lane = tid & 63;
  const int r15 = lane & 15, g4 = lane >> 4;
  const int i0 = blockIdx.x * 128, j0 = blockIdx.y * 128;
  const int wm = (wave >> 1) * 64, wn = (wave & 1) * 64;

  auto stage = [&](int k0, int buf) {
#pragma unroll
    for (int c = 0; c < 2; ++c) {
      int ch = (wave * 2 + c) * 64 + lane;
      int row = ch >> 2, cg = ch & 3;
      async16(A + (size_t)(i0 + row) * 1024 + k0 + cg * 8, &At[buf][0] + (wave * 2 + c) * 512);
      async16(Bw + (size_t)(j0 + row) * 1024 + k0 + cg * 8, &Bt[buf][0] + (wave * 2 + c) * 512);
    }
  };

  f32x4 acc[4][4];
#pragma unroll
  for (int m = 0; m < 4; ++m)
#pragma unroll
    for (int n = 0; n < 4; ++n) acc[m][n] = (f32x4){0.f, 0.f, 0.f, 0.f};

  stage(0, 0);
  __syncthreads();

  for (int it = 0; it < 32; ++it) {
    const int cur = it & 1, nxt = cur ^ 1;
    if (it < 31) stage((it + 1) * 32, nxt);  // overlap with compute below
    bf16x8 af[4], bf[4];
#pragma unroll
    for (int m = 0; m < 4; ++m)
      af[m] = *(const bf16x8*)(&At[cur][(wm + m * 16 + r15) * 32 + g4 * 8]);
#pragma unroll
    for (int n = 0; n < 4; ++n)
      bf[n] = *(const bf16x8*)(&Bt[cur][(wn + n * 16 + r15) * 32 + g4 * 8]);
    __builtin_amdgcn_s_setprio(1);
#pragma unroll
    for (int m = 0; m < 4; ++m)
#pragma unroll
      for (int n = 0; n < 4; ++n)
        acc[m][n] = __builtin_amdgcn_mfma_f32_16x16x32_bf16(af[m], bf[n], acc[m][n], 0, 0, 0);
    __builtin_amdgcn_s_setprio(0);
    __syncthreads();  // drains nxt-stage vmcnt + releases cur for overwrite
  }

#pragma unroll
  for (int m = 0; m < 4; ++m)
#pragma unroll
    for (int n = 0; n < 4; ++n)
#pragma unroll
      for (int r = 0; r < 4; ++r) {
        int i = i0 + wm + m * 16 + g4 * 4 + r;
        int j = j0 + wn + n * 16 + r15;
        int b = i >> 10, s = i & 1023, h = j >> 6, d = j & 63;
        Dst[(((size_t)b * 16 + h) * SS + s) * dstride + d] = f2b(acc[m][n][r] * sc);
      }
}

// ---------------- output projection GEMM: out = Oh(heads) @ Wo^T, 2-phase dbuf ----------
__global__ __launch_bounds__(256) void gemm_out(const unsigned short* __restrict__ Oh,
                                                const unsigned short* __restrict__ Wob,
                                                float* __restrict__ Out) {
  __shared__ unsigned short At[2][128 * 32];
  __shared__ unsigned short Bt[2][128 * 32];

  const int tid = threadIdx.x, wave = tid >> 6, lane = tid & 63;
  const int r15 = lane & 15, g4 = lane >> 4;
  const int i0 = blockIdx.x * 128, j0 = blockIdx.y * 128;
  const int wm = (wave >> 1) * 64, wn = (wave & 1) * 64;

  auto stage = [&](int k0, int buf) {
#pragma unroll
    for (int c = 0; c < 2; ++c) {
      int ch = (wave * 2 + c) * 64 + lane;
      int row = ch >> 2, cg = ch & 3;
      int i = i0 + row, b = i >> 10, s = i & 1023;
      int kcol = k0 + cg * 8, h = kcol >> 6, dd = kcol & 63;
      async16(Oh + (((size_t)b * 16 + h) * SS + s) * 64 + dd, &At[buf][0] + (wave * 2 + c) * 512);
      async16(Wob + (size_t)(j0 + row) * 1024 + k0 + cg * 8, &Bt[buf][0] + (wave * 2 + c) * 512);
    }
  };

  f32x4 acc[4][4];
#pragma unroll
  for (int m = 0; m < 4; ++m)
#pragma unroll
    for (int n = 0; n < 4; ++n) acc[m][n] = (f32x4){0.f, 0.f, 0.f, 0.f};

  stage(0, 0);
  __syncthreads();

  for (int it = 0; it < 32; ++it) {
    const int cur = it & 1, nxt = cur ^ 1;
    if (it < 31) stage((it + 1) * 32, nxt);
    bf16x8 af[4], bf[4];
#pragma unroll
    for (int m = 0; m < 4; ++m)
      af[m] = *(const bf16x8*)(&At[cur][(wm + m * 16 + r15) * 32 + g4 * 8]);
#pragma unroll
    for (int n = 0; n < 4; ++n)
      bf[n] = *(const bf16x8*)(&Bt[cur][(wn + n * 16 + r15) * 32 + g4 * 8]);
    __builtin_amdgcn_s_setprio(1);
#pragma unroll
    for (int m = 0; m < 4; ++m)
#pragma unroll
      for (int n = 0; n < 4; ++n)
        acc[m][n] = __builtin_amdgcn_mfma_f32_16x16x32_bf16(af[m], bf[n], acc[m][n], 0, 0, 0);
    __builtin_amdgcn_s_setprio(0);
    __syncthreads();
  }

#pragma unroll
  for (int m = 0; m < 4; ++m)
#pragma unroll
    for (int n = 0; n < 4; ++n)
#pragma unroll
      for (int r = 0; r < 4; ++r) {
        int i = i0 + wm + m * 16 + g4 * 4 + r;
        int j = j0 + wn + n * 16 + r15;
        Out[(size_t)i * 1024 + j] = acc[m][n][r];
      }
}

// ---------------- rank-34 augmentation via MFMA ----------------
__global__ __launch_bounds__(256) void aug_dots_mfma(unsigned short* __restrict__ T,
                                                     const float* __restrict__ rel,
                                                     int cbase) {
  const int bh = blockIdx.y, h = bh & 15, s0 = blockIdx.x * 128;
  const int tid = threadIdx.x, wave = tid >> 6, lane = tid & 63;
  const int r15 = lane & 15, g4 = lane >> 4;

  __shared__ unsigned short RL[48 * 72];  // rel[h] bf16, rows padded to 48, stride 72
  for (int idx = tid; idx < 48 * 64; idx += 256) {
    int r = idx >> 6, d = idx & 63;
    RL[r * 72 + d] = (r < 34) ? f2b(rel[((size_t)h * 34 + r) * 64 + d]) : (unsigned short)0;
  }
  __syncthreads();

  bf16x8 bfr[3][2];
#pragma unroll
  for (int n = 0; n < 3; ++n)
#pragma unroll
    for (int st = 0; st < 2; ++st)
      bfr[n][st] = *(const bf16x8*)(RL + (n * 16 + r15) * 72 + st * 32 + g4 * 8);

  f32x4 acc[2][3];
#pragma unroll
  for (int m = 0; m < 2; ++m)
#pragma unroll
    for (int n = 0; n < 3; ++n) acc[m][n] = (f32x4){0.f, 0.f, 0.f, 0.f};

#pragma unroll
  for (int m = 0; m < 2; ++m) {
    const unsigned short* Arow = T + ((size_t)bh * SS + s0 + wave * 32 + m * 16 + r15) * DAUG;
    bf16x8 a0 = *(const bf16x8*)(Arow + g4 * 8);
    bf16x8 a1 = *(const bf16x8*)(Arow + 32 + g4 * 8);
#pragma unroll
    for (int n = 0; n < 3; ++n) {
      acc[m][n] = __builtin_amdgcn_mfma_f32_16x16x32_bf16(a0, bfr[n][0], acc[m][n], 0, 0, 0);
      acc[m][n] = __builtin_amdgcn_mfma_f32_16x16x32_bf16(a1, bfr[n][1], acc[m][n], 0, 0, 0);
    }
  }

#pragma unroll
  for (int m = 0; m < 2; ++m)
#pragma unroll
    for (int n = 0; n < 3; ++n) {
      int col = n * 16 + r15;
      if (col < 34) {
#pragma unroll
        for (int r = 0; r < 4; ++r) {
          int row = s0 + wave * 32 + m * 16 + g4 * 4 + r;
          T[((size_t)bh * SS + row) * DAUG + cbase + col] = f2b(acc[m][n][r]);
        }
      }
    }
}

// ---------------- fused pos transpose-copy + zero pad (+ optional V' update) -------------
__global__ __launch_bounds__(256) void pos_fuse(unsigned short* __restrict__ T,
                                                const float* __restrict__ Pe,
                                                const float* __restrict__ Pp, int cbase,
                                                float scale, unsigned short* __restrict__ Vp,
                                                const float* __restrict__ relv) {
  const int bh = blockIdx.y, h = bh & 15, s0 = blockIdx.x * 64;
  const int tid = threadIdx.x;
  __shared__ float PeL[17][65];
  __shared__ float PpL[17][65];

  for (int idx = tid; idx < 17 * 64; idx += 256) {
    int r = idx >> 6, c = idx & 63;
    PeL[r][c] = Pe[((size_t)bh * 17 + r) * SS + s0 + c];
    PpL[r][c] = Pp[((size_t)bh * 17 + r) * SS + s0 + c];
  }
  __syncthreads();

  for (int idx = tid; idx < 4096; idx += 256) {
    int s = idx >> 6, j = idx & 63;
    if (j < 34) {
      float v = (j < 17) ? PeL[j][s] : PpL[j - 17][s];
      T[((size_t)bh * SS + s0 + s) * DAUG + cbase + j] = f2b(v * scale);
    } else if (j < 62) {
      T[((size_t)bh * SS + s0 + s) * DAUG + 132 + (j - 34)] = 0;
    }
  }

  if (Vp != nullptr) {
    const int d = tid & 63, sg = tid >> 6;
    float acc[16];
#pragma unroll
    for (int si = 0; si < 16; ++si) acc[si] = 0.f;
    for (int r = 0; r < 17; ++r) {
      float ve = relv[((size_t)h * 34 + r) * 64 + d];
      float vp = relv[((size_t)h * 34 + 17 + r) * 64 + d];
#pragma unroll
      for (int si = 0; si < 16; ++si) {
        int s = sg * 16 + si;
        acc[si] += PeL[r][s] * ve + PpL[r][s] * vp;
      }
    }
#pragma unroll
    for (int si = 0; si < 16; ++si) {
      size_t o = ((size_t)bh * SS + s0 + sg * 16 + si) * 64 + d;
      Vp[o] = f2b(b2f(Vp[o]) + acc[si]);
    }
  }
}

// ---------------- flash attention v4 ----------------
// v3 + T13 defer-rescale (THR=8, exp2 domain) + T5 setprio around MFMA clusters.
__global__ __launch_bounds__(512, 4) void flash_attn2(
    const unsigned short* __restrict__ Qt, const unsigned short* __restrict__ Kt,
    const unsigned short* __restrict__ Vp, unsigned short* __restrict__ Oh) {
  const int bh = blockIdx.y;
  const int q0 = blockIdx.x * 128;
  const int tid = threadIdx.x, wave = tid >> 6, lane = tid & 63;
  const int r15 = lane & 15, g4 = lane >> 4;

  __shared__ unsigned short Ks[2][64 * 160];
  __shared__ unsigned short Vs[2][64 * 72];
  __shared__ unsigned short Ps[128 * 72];
  __shared__ unsigned short Vones[16 * 72];  // row 0 = 1.0, rows 1..15 = 0

  for (int idx = tid; idx < 16 * 72; idx += 512)
    Vones[idx] = (idx < 72) ? (unsigned short)0x3F80 : (unsigned short)0;

  const unsigned short* Kbase = Kt + (size_t)bh * SS * DAUG;
  const unsigned short* Vbase = Vp + (size_t)bh * SS * 64;

  bf16x8 qf[5];
  {
    const unsigned short* Qg = Qt + ((size_t)bh * SS + q0 + wave * 16 + r15) * DAUG;
#pragma unroll
    for (int kk = 0; kk < 5; ++kk) qf[kk] = *(const bf16x8*)(Qg + kk * 32 + g4 * 8);
  }

  auto stageK = [&](int kv0, int buf) {
    const unsigned short* Kg = Kbase + (size_t)kv0 * DAUG;
#pragma unroll
    for (int j = 0; j < 2; ++j) {
      int ibase = j * 512 + wave * 64;
      int i = ibase + lane;
      int row = i / 20, c = i % 20;
      int cs = (c < 16) ? (c ^ (row & 7)) : (16 + ((c & 3) ^ (row & 3)));
      async16(Kg + (size_t)row * DAUG + cs * 8, &Ks[buf][0] + (size_t)ibase * 8);
    }
    if (wave < 4) {
      int ibase = 1024 + wave * 64;
      int i = ibase + lane;
      int row = i / 20, c = i % 20;
      int cs = (c < 16) ? (c ^ (row & 7)) : (16 + ((c & 3) ^ (row & 3)));
      async16(Kg + (size_t)row * DAUG + cs * 8, &Ks[buf][0] + (size_t)ibase * 8);
    }
  };
  auto writeVT = [&](int buf, uint4 v) {
    const unsigned short* hv = (const unsigned short*)&v;
    int vrow = tid >> 3, d0 = (tid & 7) * 8;
#pragma unroll
    for (int j = 0; j < 8; ++j) Vs[buf][(d0 + j) * 72 + vrow] = hv[j];
  };

  stageK(0, 0);
  uint4 vreg = *(const uint4*)(Vbase + tid * 8);
  writeVT(0, vreg);
  __syncthreads();

  f32x4 accO[5];
#pragma unroll
  for (int df = 0; df < 5; ++df) accO[df] = (f32x4){0.f, 0.f, 0.f, 0.f};
  float run_m[4] = {-INFINITY, -INFINITY, -INFINITY, -INFINITY};

  for (int t = 0; t < 16; ++t) {
    const int cur = t & 1, nxt = cur ^ 1;
    if (t < 15) {
      stageK((t + 1) * 64, nxt);
      vreg = *(const uint4*)(Vbase + (size_t)(t + 1) * 64 * 64 + tid * 8);
    }

    f32x4 s[4];
#pragma unroll
    for (int f = 0; f < 4; ++f) s[f] = (f32x4){0.f, 0.f, 0.f, 0.f};
    __builtin_amdgcn_s_setprio(1);
#pragma unroll
    for (int f = 0; f < 4; ++f) {
      int row = f * 16 + r15;
#pragma unroll
      for (int kk = 0; kk < 5; ++kk) {
        int c = kk * 4 + g4;
        int cs = (c < 16) ? (c ^ (row & 7)) : (16 + ((c & 3) ^ (row & 3)));
        bf16x8 kf = *(const bf16x8*)(&Ks[cur][(size_t)row * DAUG + cs * 8]);
        s[f] = __builtin_amdgcn_mfma_f32_16x16x32_bf16(qf[kk], kf, s[f], 0, 0, 0);
      }
    }
    __builtin_amdgcn_s_setprio(0);

    // row max (per 16-lane group; rows = g4*4 + r)
    float mx[4];
#pragma unroll
    for (int r = 0; r < 4; ++r) {
      float m0 = fmaxf(fmaxf(s[0][r], s[1][r]), fmaxf(s[2][r], s[3][r]));
#pragma unroll
      for (int off = 1; off < 16; off <<= 1) m0 = fmaxf(m0, __shfl_xor(m0, off, 64));
      mx[r] = m0;
    }
    // T13 defer-rescale: only pay corr + accO rescale when max grew past THR=8
    bool stable = (mx[0] <= run_m[0] + 8.f) && (mx[1] <= run_m[1] + 8.f) &&
                  (mx[2] <= run_m[2] + 8.f) && (mx[3] <= run_m[3] + 8.f);
    if (!__all(stable)) {
#pragma unroll
      for (int r = 0; r < 4; ++r) {
        float mnew = fmaxf(run_m[r], mx[r]);
        float corr = exp2f(run_m[r] - mnew);
        run_m[r] = mnew;
#pragma unroll
        for (int df = 0; df < 5; ++df) accO[df][r] *= corr;
      }
    }
#pragma unroll
    for (int r = 0; r < 4; ++r)
#pragma unroll
      for (int f = 0; f < 4; ++f) s[f][r] = exp2f(s[f][r] - run_m[r]);

#pragma unroll
    for (int f = 0; f < 4; ++f)
#pragma unroll
      for (int r = 0; r < 4; ++r)
        ((__bf16*)Ps)[(wave * 16 + g4 * 4 + r) * 72 + f * 16 + r15] = (__bf16)s[f][r];

    __builtin_amdgcn_s_setprio(1);
#pragma unroll
    for (int ks = 0; ks < 2; ++ks) {
      bf16x8 pa = *(const bf16x8*)(Ps + (wave * 16 + r15) * 72 + ks * 32 + g4 * 8);
#pragma unroll
      for (int df = 0; df < 4; ++df) {
        bf16x8 vb = *(const bf16x8*)(&Vs[cur][(df * 16 + r15) * 72 + ks * 32 + g4 * 8]);
        accO[df] = __builtin_amdgcn_mfma_f32_16x16x32_bf16(pa, vb, accO[df], 0, 0, 0);
      }
      bf16x8 vb1 = *(const bf16x8*)(Vones + r15 * 72 + ks * 32 + g4 * 8);
      accO[4] = __builtin_amdgcn_mfma_f32_16x16x32_bf16(pa, vb1, accO[4], 0, 0, 0);
    }
    __builtin_amdgcn_s_setprio(0);

    if (t < 15) writeVT(nxt, vreg);
    __syncthreads();
  }

  float rl[4];
#pragma unroll
  for (int r = 0; r < 4; ++r) {
    float l = __shfl(accO[4][r], lane & 48, 64);  // col 64 (=sum) lives at r15==0
    rl[r] = 1.f / l;
  }
#pragma unroll
  for (int df = 0; df < 4; ++df)
#pragma unroll
    for (int r = 0; r < 4; ++r) {
      float o = accO[df][r] * rl[r];
      Oh[((size_t)bh * SS + q0 + wave * 16 + g4 * 4 + r) * 64 + df * 16 + r15] = f2b(o);
    }
}

extern "C" void kernel_launch(void* const* d_in, const int* in_sizes, int n_in,
                              void* d_out, int out_size, void* d_ws, size_t ws_size,
                              hipStream_t stream) {
  const float* query = (const float*)d_in[0];
  const float* key = (const float*)d_in[1];
  const float* value = (const float*)d_in[2];
  const float* pe = (const float*)d_in[3];
  const float* pp = (const float*)d_in[4];
  const float* cpe = (const float*)d_in[5];
  const float* cpp = (const float*)d_in[6];
  const float* relq = (const float*)d_in[7];
  const float* relk = (const float*)d_in[8];
  const float* relv = (const float*)d_in[9];
  const float* Wq = (const float*)d_in[10];
  const float* Wk = (const float*)d_in[11];
  const float* Wv = (const float*)d_in[12];
  const float* Wo = (const float*)d_in[13];
  float* out = (float*)d_out;
  char* ws = (char*)d_ws;

  unsigned short* Xq = (unsigned short*)(ws + 0);
  unsigned short* Xk = (unsigned short*)(ws + 8388608);
  unsigned short* Xv = (unsigned short*)(ws + 16777216);
  unsigned short* Wqb = (unsigned short*)(ws + 25165824);
  unsigned short* Wkb = (unsigned short*)(ws + 27262976);
  unsigned short* Wvb = (unsigned short*)(ws + 29360128);
  unsigned short* Wob = (unsigned short*)(ws + 31457280);
  unsigned short* Qt = (unsigned short*)(ws + 33554432);
  unsigned short* Kt = (unsigned short*)(ws + 54525952);
  unsigned short* Vp = (unsigned short*)(ws + 75497472);
  unsigned short* Oh = (unsigned short*)(ws + 0);  // alias Xq (dead after proj_qkv)

  convert7<<<dim3(1024, 7, 1), 256, 0, stream>>>(query, key, value, Wq, Wk, Wv, Wo, Xq, Xk, Xv,
                                                 Wqb, Wkb, Wvb, Wob);
  proj_qkv<<<dim3(32, 8, 3), 256, 0, stream>>>(Xq, Xk, Xv, Wqb, Wkb, Wvb, Qt, Kt, Vp);
  aug_dots_mfma<<<dim3(8, 64, 1), 256, 0, stream>>>(Qt, relk, 64);   // Q~ cols 64..97
  aug_dots_mfma<<<dim3(8, 64, 1), 256, 0, stream>>>(Kt, relq, 98);   // K~ cols 98..131
  pos_fuse<<<dim3(16, 64, 1), 256, 0, stream>>>(Qt, cpe, cpp, 98, KAPPA, nullptr, nullptr);
  pos_fuse<<<dim3(16, 64, 1), 256, 0, stream>>>(Kt, pe, pp, 64, 1.0f, Vp, relv);
  flash_attn2<<<dim3(8, 64, 1), 512, 0, stream>>>(Qt, Kt, Vp, Oh);
  gemm_out<<<dim3(32, 8, 1), 256, 0, stream>>>(Oh, Wob, out);
}

// Round 6
// 177.066 us; speedup vs baseline: 1.1037x; 1.1037x over previous
//
#include <hip/hip_runtime.h>
#include <hip/hip_bf16.h>
#include <stdint.h>

typedef float f32x4 __attribute__((ext_vector_type(4)));
typedef __bf16 bf16x8 __attribute__((ext_vector_type(8)));

#define NBH 64      // B*H
#define SS 1024     // SQ == SKV
#define DAUG 160    // augmented head dim 132 padded to 160
#define KAPPA 0.18033688011104293f  // 0.125 * log2(e), folded into Q~

static __device__ __forceinline__ unsigned short f2b(float f) {
  union { float f; uint32_t u; } v; v.f = f;
  return (unsigned short)((v.u + 0x7fffu + ((v.u >> 16) & 1u)) >> 16);
}
static __device__ __forceinline__ float b2f(unsigned short s) {
  union { uint32_t u; float f; } v; v.u = ((uint32_t)s) << 16;
  return v.f;
}

static __device__ __forceinline__ void async16(const void* g, void* l) {
  __builtin_amdgcn_global_load_lds(
      (const __attribute__((address_space(1))) uint32_t*)g,
      (__attribute__((address_space(3))) uint32_t*)l, 16, 0, 0);
}

// DPP max-reduce over 16-lane rows (VALU pipe, no LDS traffic).
template <int CTRL>
static __device__ __forceinline__ float dppmaxstep(float x) {
  int y = __builtin_amdgcn_update_dpp(__builtin_bit_cast(int, x), __builtin_bit_cast(int, x),
                                      CTRL, 0xF, 0xF, false);
  return fmaxf(x, __builtin_bit_cast(float, y));
}
static __device__ __forceinline__ float rowmax16(float x) {
  x = dppmaxstep<0x128>(x);  // row_ror:8
  x = dppmaxstep<0x124>(x);  // row_ror:4
  x = dppmaxstep<0x122>(x);  // row_ror:2
  x = dppmaxstep<0x121>(x);  // row_ror:1
  return x;
}

// ---------------- f32 -> bf16 conversion for 7 tensors ----------------
__global__ void convert7(const float* q, const float* k, const float* v,
                         const float* wq, const float* wk, const float* wv, const float* wo,
                         unsigned short* xq, unsigned short* xk, unsigned short* xv,
                         unsigned short* bwq, unsigned short* bwk, unsigned short* bwv,
                         unsigned short* bwo) {
  const float* s; unsigned short* d; int n;
  switch (blockIdx.y) {
    case 0: s = q;  d = xq;  n = 4194304; break;
    case 1: s = k;  d = xk;  n = 4194304; break;
    case 2: s = v;  d = xv;  n = 4194304; break;
    case 3: s = wq; d = bwq; n = 1048576; break;
    case 4: s = wk; d = bwk; n = 1048576; break;
    case 5: s = wv; d = bwv; n = 1048576; break;
    default: s = wo; d = bwo; n = 1048576; break;
  }
  int n4 = n >> 2;
  for (int i = blockIdx.x * blockDim.x + threadIdx.x; i < n4; i += gridDim.x * blockDim.x) {
    float4 f = ((const float4*)s)[i];
    ushort4 o;
    o.x = f2b(f.x); o.y = f2b(f.y); o.z = f2b(f.z); o.w = f2b(f.w);
    ((ushort4*)d)[i] = o;
  }
}

// ---------------- QKV projection GEMM: Y = X @ W^T, 2-phase dbuf ----------------
__global__ __launch_bounds__(256) void proj_qkv(
    const unsigned short* __restrict__ Xq, const unsigned short* __restrict__ Xk,
    const unsigned short* __restrict__ Xv, const unsigned short* __restrict__ Wqb,
    const unsigned short* __restrict__ Wkb, const unsigned short* __restrict__ Wvb,
    unsigned short* __restrict__ Qt, unsigned short* __restrict__ Kt,
    unsigned short* __restrict__ Vp) {
  const int z = blockIdx.z;
  const unsigned short* A = (z == 0) ? Xq : (z == 1) ? Xk : Xv;
  const unsigned short* Bw = (z == 0) ? Wqb : (z == 1) ? Wkb : Wvb;
  unsigned short* Dst = (z == 0) ? Qt : (z == 1) ? Kt : Vp;
  const int dstride = (z == 2) ? 64 : DAUG;
  const float sc = (z == 0) ? KAPPA : 1.0f;

  __shared__ unsigned short At[2][128 * 32];
  __shared__ unsigned short Bt[2][128 * 32];

  const int tid = threadIdx.x, wave = tid >> 6, lane = tid & 63;
  const int r15 = lane & 15, g4 = lane >> 4;
  const int i0 = blockIdx.x * 128, j0 = blockIdx.y * 128;
  const int wm = (wave >> 1) * 64, wn = (wave & 1) * 64;

  auto stage = [&](int k0, int buf) {
#pragma unroll
    for (int c = 0; c < 2; ++c) {
      int ch = (wave * 2 + c) * 64 + lane;
      int row = ch >> 2, cg = ch & 3;
      async16(A + (size_t)(i0 + row) * 1024 + k0 + cg * 8, &At[buf][0] + (wave * 2 + c) * 512);
      async16(Bw + (size_t)(j0 + row) * 1024 + k0 + cg * 8, &Bt[buf][0] + (wave * 2 + c) * 512);
    }
  };

  f32x4 acc[4][4];
#pragma unroll
  for (int m = 0; m < 4; ++m)
#pragma unroll
    for (int n = 0; n < 4; ++n) acc[m][n] = (f32x4){0.f, 0.f, 0.f, 0.f};

  stage(0, 0);
  __syncthreads();

  for (int it = 0; it < 32; ++it) {
    const int cur = it & 1, nxt = cur ^ 1;
    if (it < 31) stage((it + 1) * 32, nxt);
    bf16x8 af[4], bf[4];
#pragma unroll
    for (int m = 0; m < 4; ++m)
      af[m] = *(const bf16x8*)(&At[cur][(wm + m * 16 + r15) * 32 + g4 * 8]);
#pragma unroll
    for (int n = 0; n < 4; ++n)
      bf[n] = *(const bf16x8*)(&Bt[cur][(wn + n * 16 + r15) * 32 + g4 * 8]);
    __builtin_amdgcn_s_setprio(1);
#pragma unroll
    for (int m = 0; m < 4; ++m)
#pragma unroll
      for (int n = 0; n < 4; ++n)
        acc[m][n] = __builtin_amdgcn_mfma_f32_16x16x32_bf16(af[m], bf[n], acc[m][n], 0, 0, 0);
    __builtin_amdgcn_s_setprio(0);
    __syncthreads();
  }

#pragma unroll
  for (int m = 0; m < 4; ++m)
#pragma unroll
    for (int n = 0; n < 4; ++n)
#pragma unroll
      for (int r = 0; r < 4; ++r) {
        int i = i0 + wm + m * 16 + g4 * 4 + r;
        int j = j0 + wn + n * 16 + r15;
        int b = i >> 10, s = i & 1023, h = j >> 6, d = j & 63;
        Dst[(((size_t)b * 16 + h) * SS + s) * dstride + d] = f2b(acc[m][n][r] * sc);
      }
}

// ---------------- output projection GEMM: out = Oh(heads) @ Wo^T, 2-phase dbuf ----------
__global__ __launch_bounds__(256) void gemm_out(const unsigned short* __restrict__ Oh,
                                                const unsigned short* __restrict__ Wob,
                                                float* __restrict__ Out) {
  __shared__ unsigned short At[2][128 * 32];
  __shared__ unsigned short Bt[2][128 * 32];

  const int tid = threadIdx.x, wave = tid >> 6, lane = tid & 63;
  const int r15 = lane & 15, g4 = lane >> 4;
  const int i0 = blockIdx.x * 128, j0 = blockIdx.y * 128;
  const int wm = (wave >> 1) * 64, wn = (wave & 1) * 64;

  auto stage = [&](int k0, int buf) {
#pragma unroll
    for (int c = 0; c < 2; ++c) {
      int ch = (wave * 2 + c) * 64 + lane;
      int row = ch >> 2, cg = ch & 3;
      int i = i0 + row, b = i >> 10, s = i & 1023;
      int kcol = k0 + cg * 8, h = kcol >> 6, dd = kcol & 63;
      async16(Oh + (((size_t)b * 16 + h) * SS + s) * 64 + dd, &At[buf][0] + (wave * 2 + c) * 512);
      async16(Wob + (size_t)(j0 + row) * 1024 + k0 + cg * 8, &Bt[buf][0] + (wave * 2 + c) * 512);
    }
  };

  f32x4 acc[4][4];
#pragma unroll
  for (int m = 0; m < 4; ++m)
#pragma unroll
    for (int n = 0; n < 4; ++n) acc[m][n] = (f32x4){0.f, 0.f, 0.f, 0.f};

  stage(0, 0);
  __syncthreads();

  for (int it = 0; it < 32; ++it) {
    const int cur = it & 1, nxt = cur ^ 1;
    if (it < 31) stage((it + 1) * 32, nxt);
    bf16x8 af[4], bf[4];
#pragma unroll
    for (int m = 0; m < 4; ++m)
      af[m] = *(const bf16x8*)(&At[cur][(wm + m * 16 + r15) * 32 + g4 * 8]);
#pragma unroll
    for (int n = 0; n < 4; ++n)
      bf[n] = *(const bf16x8*)(&Bt[cur][(wn + n * 16 + r15) * 32 + g4 * 8]);
    __builtin_amdgcn_s_setprio(1);
#pragma unroll
    for (int m = 0; m < 4; ++m)
#pragma unroll
      for (int n = 0; n < 4; ++n)
        acc[m][n] = __builtin_amdgcn_mfma_f32_16x16x32_bf16(af[m], bf[n], acc[m][n], 0, 0, 0);
    __builtin_amdgcn_s_setprio(0);
    __syncthreads();
  }

#pragma unroll
  for (int m = 0; m < 4; ++m)
#pragma unroll
    for (int n = 0; n < 4; ++n)
#pragma unroll
      for (int r = 0; r < 4; ++r) {
        int i = i0 + wm + m * 16 + g4 * 4 + r;
        int j = j0 + wn + n * 16 + r15;
        Out[(size_t)i * 1024 + j] = acc[m][n][r];
      }
}

// ---------------- rank-34 augmentation via MFMA (merged Q/K via grid.z) ----------------
__global__ __launch_bounds__(256) void aug_dots_mfma2(unsigned short* __restrict__ Qt,
                                                      unsigned short* __restrict__ Kt,
                                                      const float* __restrict__ relk,
                                                      const float* __restrict__ relq) {
  const int z = blockIdx.z;
  unsigned short* T = z ? Kt : Qt;
  const float* rel = z ? relq : relk;
  const int cbase = z ? 98 : 64;
  const int bh = blockIdx.y, h = bh & 15, s0 = blockIdx.x * 128;
  const int tid = threadIdx.x, wave = tid >> 6, lane = tid & 63;
  const int r15 = lane & 15, g4 = lane >> 4;

  __shared__ unsigned short RL[48 * 72];
  for (int idx = tid; idx < 48 * 64; idx += 256) {
    int r = idx >> 6, d = idx & 63;
    RL[r * 72 + d] = (r < 34) ? f2b(rel[((size_t)h * 34 + r) * 64 + d]) : (unsigned short)0;
  }
  __syncthreads();

  bf16x8 bfr[3][2];
#pragma unroll
  for (int n = 0; n < 3; ++n)
#pragma unroll
    for (int st = 0; st < 2; ++st)
      bfr[n][st] = *(const bf16x8*)(RL + (n * 16 + r15) * 72 + st * 32 + g4 * 8);

  f32x4 acc[2][3];
#pragma unroll
  for (int m = 0; m < 2; ++m)
#pragma unroll
    for (int n = 0; n < 3; ++n) acc[m][n] = (f32x4){0.f, 0.f, 0.f, 0.f};

#pragma unroll
  for (int m = 0; m < 2; ++m) {
    const unsigned short* Arow = T + ((size_t)bh * SS + s0 + wave * 32 + m * 16 + r15) * DAUG;
    bf16x8 a0 = *(const bf16x8*)(Arow + g4 * 8);
    bf16x8 a1 = *(const bf16x8*)(Arow + 32 + g4 * 8);
#pragma unroll
    for (int n = 0; n < 3; ++n) {
      acc[m][n] = __builtin_amdgcn_mfma_f32_16x16x32_bf16(a0, bfr[n][0], acc[m][n], 0, 0, 0);
      acc[m][n] = __builtin_amdgcn_mfma_f32_16x16x32_bf16(a1, bfr[n][1], acc[m][n], 0, 0, 0);
    }
  }

#pragma unroll
  for (int m = 0; m < 2; ++m)
#pragma unroll
    for (int n = 0; n < 3; ++n) {
      int col = n * 16 + r15;
      if (col < 34) {
#pragma unroll
        for (int r = 0; r < 4; ++r) {
          int row = s0 + wave * 32 + m * 16 + g4 * 4 + r;
          T[((size_t)bh * SS + row) * DAUG + cbase + col] = f2b(acc[m][n][r]);
        }
      }
    }
}

// ---------------- pos transpose-copy + zero pad (merged Q/K via grid.z) -------------
__global__ __launch_bounds__(256) void pos_copy2(unsigned short* __restrict__ Qt,
                                                 unsigned short* __restrict__ Kt,
                                                 const float* __restrict__ cpe,
                                                 const float* __restrict__ cpp,
                                                 const float* __restrict__ pe,
                                                 const float* __restrict__ pp) {
  const int z = blockIdx.z;
  unsigned short* T = z ? Kt : Qt;
  const float* Pe = z ? pe : cpe;
  const float* Pp = z ? pp : cpp;
  const int cbase = z ? 64 : 98;
  const float scale = z ? 1.0f : KAPPA;
  const int bh = blockIdx.y, s0 = blockIdx.x * 64;
  const int tid = threadIdx.x;
  __shared__ float PeL[17][65];
  __shared__ float PpL[17][65];

  for (int idx = tid; idx < 17 * 64; idx += 256) {
    int r = idx >> 6, c = idx & 63;
    PeL[r][c] = Pe[((size_t)bh * 17 + r) * SS + s0 + c];
    PpL[r][c] = Pp[((size_t)bh * 17 + r) * SS + s0 + c];
  }
  __syncthreads();

  for (int idx = tid; idx < 4096; idx += 256) {
    int s = idx >> 6, j = idx & 63;
    if (j < 34) {
      float v = (j < 17) ? PeL[j][s] : PpL[j - 17][s];
      T[((size_t)bh * SS + s0 + s) * DAUG + cbase + j] = f2b(v * scale);
    } else if (j < 62) {
      T[((size_t)bh * SS + s0 + s) * DAUG + 132 + (j - 34)] = 0;
    }
  }
}

// ---------------- V' build, transposed: VpT[bh][d 0..79][s] ----------------
// rows 0..63 = (V + pos^T@rv)^T ; row 64 = ones ; rows 65..79 = zeros.
__global__ __launch_bounds__(256) void vprime_T(const unsigned short* __restrict__ Vp,
                                                const float* __restrict__ Pe,
                                                const float* __restrict__ Pp,
                                                const float* __restrict__ relv,
                                                unsigned short* __restrict__ VpT) {
  const int bh = blockIdx.y, h = bh & 15, s0 = blockIdx.x * 64;
  const int tid = threadIdx.x;
  __shared__ float PeL[17][65];
  __shared__ float PpL[17][65];
  __shared__ unsigned short VT[64][72];  // [d][s-local]

  for (int idx = tid; idx < 17 * 64; idx += 256) {
    int r = idx >> 6, c = idx & 63;
    PeL[r][c] = Pe[((size_t)bh * 17 + r) * SS + s0 + c];
    PpL[r][c] = Pp[((size_t)bh * 17 + r) * SS + s0 + c];
  }
  __syncthreads();

  const int d = tid & 63, sg = tid >> 6;
  float acc[16];
#pragma unroll
  for (int si = 0; si < 16; ++si) acc[si] = 0.f;
  for (int r = 0; r < 17; ++r) {
    float ve = relv[((size_t)h * 34 + r) * 64 + d];
    float vpv = relv[((size_t)h * 34 + 17 + r) * 64 + d];
#pragma unroll
    for (int si = 0; si < 16; ++si) {
      int s = sg * 16 + si;
      acc[si] += PeL[r][s] * ve + PpL[r][s] * vpv;
    }
  }
#pragma unroll
  for (int si = 0; si < 16; ++si) {
    int s = sg * 16 + si;
    float v = b2f(Vp[((size_t)bh * SS + s0 + s) * 64 + d]) + acc[si];
    VT[d][s] = f2b(v);
  }
  __syncthreads();

  // coalesced global write of the 64 data rows
  for (int c = tid; c < 512; c += 256) {
    int row = c >> 3, c8 = c & 7;
    uint4 v = *(const uint4*)&VT[row][c8 * 8];
    *(uint4*)(VpT + ((size_t)bh * 80 + row) * 1024 + s0 + c8 * 8) = v;
  }
  // ones row (64) + zero rows (65..79)
  if (tid < 128) {
    int row = 64 + (tid >> 3), c8 = tid & 7;
    uint32_t w = (row == 64) ? 0x3F803F80u : 0u;
    uint4 v = {w, w, w, w};
    *(uint4*)(VpT + ((size_t)bh * 80 + row) * 1024 + s0 + c8 * 8) = v;
  }
}

// ---------------- flash attention v5 ----------------
// K and V^T both staged via global_load_lds (source-XOR-swizzled, linear LDS);
// no V ds_writes, no Vones (ones row folded into VpT); DPP max-reduce;
// T13 defer-rescale; T5 setprio; one barrier per kv-step.
__global__ __launch_bounds__(512, 4) void flash_attn3(
    const unsigned short* __restrict__ Qt, const unsigned short* __restrict__ Kt,
    const unsigned short* __restrict__ VpT, unsigned short* __restrict__ Oh) {
  const int bh = blockIdx.y;
  const int q0 = blockIdx.x * 128;
  const int tid = threadIdx.x, wave = tid >> 6, lane = tid & 63;
  const int r15 = lane & 15, g4 = lane >> 4;

  __shared__ unsigned short Ks[2][64 * 160];
  __shared__ unsigned short Vs[2][80 * 64];  // V^T tile: [d 0..79][kv 0..63], linear
  __shared__ unsigned short Ps[128 * 72];

  const unsigned short* Kbase = Kt + (size_t)bh * SS * DAUG;
  const unsigned short* Vbase = VpT + (size_t)bh * 80 * 1024;

  bf16x8 qf[5];
  {
    const unsigned short* Qg = Qt + ((size_t)bh * SS + q0 + wave * 16 + r15) * DAUG;
#pragma unroll
    for (int kk = 0; kk < 5; ++kk) qf[kk] = *(const bf16x8*)(Qg + kk * 32 + g4 * 8);
  }

  auto stageK = [&](int kv0, int buf) {
    const unsigned short* Kg = Kbase + (size_t)kv0 * DAUG;
#pragma unroll
    for (int j = 0; j < 2; ++j) {
      int ibase = j * 512 + wave * 64;
      int i = ibase + lane;
      int row = i / 20, c = i % 20;
      int cs = (c < 16) ? (c ^ (row & 7)) : (16 + ((c & 3) ^ (row & 3)));
      async16(Kg + (size_t)row * DAUG + cs * 8, &Ks[buf][0] + (size_t)ibase * 8);
    }
    if (wave < 4) {
      int ibase = 1024 + wave * 64;
      int i = ibase + lane;
      int row = i / 20, c = i % 20;
      int cs = (c < 16) ? (c ^ (row & 7)) : (16 + ((c & 3) ^ (row & 3)));
      async16(Kg + (size_t)row * DAUG + cs * 8, &Ks[buf][0] + (size_t)ibase * 8);
    }
  };
  auto stageV = [&](int kv0, int buf) {
    {
      int c = tid;  // chunks 0..511
      int row = c >> 3, c8 = c & 7;
      async16(Vbase + (size_t)row * 1024 + kv0 + ((c8 ^ (row & 7)) << 3),
              &Vs[buf][0] + (size_t)c * 8);
    }
    if (tid < 128) {  // chunks 512..639
      int c = 512 + tid;
      int row = c >> 3, c8 = c & 7;
      async16(Vbase + (size_t)row * 1024 + kv0 + ((c8 ^ (row & 7)) << 3),
              &Vs[buf][0] + (size_t)c * 8);
    }
  };

  stageK(0, 0);
  stageV(0, 0);
  __syncthreads();

  f32x4 accO[5];
#pragma unroll
  for (int df = 0; df < 5; ++df) accO[df] = (f32x4){0.f, 0.f, 0.f, 0.f};
  float run_m[4] = {-INFINITY, -INFINITY, -INFINITY, -INFINITY};

  for (int t = 0; t < 16; ++t) {
    const int cur = t & 1, nxt = cur ^ 1;
    if (t < 15) {
      stageK((t + 1) * 64, nxt);
      stageV((t + 1) * 64, nxt);
    }

    f32x4 s[4];
#pragma unroll
    for (int f = 0; f < 4; ++f) s[f] = (f32x4){0.f, 0.f, 0.f, 0.f};
    __builtin_amdgcn_s_setprio(1);
#pragma unroll
    for (int f = 0; f < 4; ++f) {
      int row = f * 16 + r15;
#pragma unroll
      for (int kk = 0; kk < 5; ++kk) {
        int c = kk * 4 + g4;
        int cs = (c < 16) ? (c ^ (row & 7)) : (16 + ((c & 3) ^ (row & 3)));
        bf16x8 kf = *(const bf16x8*)(&Ks[cur][(size_t)row * DAUG + cs * 8]);
        s[f] = __builtin_amdgcn_mfma_f32_16x16x32_bf16(qf[kk], kf, s[f], 0, 0, 0);
      }
    }
    __builtin_amdgcn_s_setprio(0);

    // row max via DPP (rows = g4*4 + r within the 16-lane group)
    float mx[4];
#pragma unroll
    for (int r = 0; r < 4; ++r)
      mx[r] = rowmax16(fmaxf(fmaxf(s[0][r], s[1][r]), fmaxf(s[2][r], s[3][r])));

    // T13 defer-rescale (THR=8, exp2 domain)
    bool stable = (mx[0] <= run_m[0] + 8.f) && (mx[1] <= run_m[1] + 8.f) &&
                  (mx[2] <= run_m[2] + 8.f) && (mx[3] <= run_m[3] + 8.f);
    if (!__all(stable)) {
#pragma unroll
      for (int r = 0; r < 4; ++r) {
        float mnew = fmaxf(run_m[r], mx[r]);
        float corr = exp2f(run_m[r] - mnew);
        run_m[r] = mnew;
#pragma unroll
        for (int df = 0; df < 5; ++df) accO[df][r] *= corr;
      }
    }
#pragma unroll
    for (int r = 0; r < 4; ++r)
#pragma unroll
      for (int f = 0; f < 4; ++f) s[f][r] = exp2f(s[f][r] - run_m[r]);

#pragma unroll
    for (int f = 0; f < 4; ++f)
#pragma unroll
      for (int r = 0; r < 4; ++r)
        ((__bf16*)Ps)[(wave * 16 + g4 * 4 + r) * 72 + f * 16 + r15] = (__bf16)s[f][r];

    __builtin_amdgcn_s_setprio(1);
#pragma unroll
    for (int ks = 0; ks < 2; ++ks) {
      bf16x8 pa = *(const bf16x8*)(Ps + (wave * 16 + r15) * 72 + ks * 32 + g4 * 8);
#pragma unroll
      for (int df = 0; df < 5; ++df) {
        int row = df * 16 + r15;
        bf16x8 vb = *(const bf16x8*)(&Vs[cur][(size_t)row * 64 + (((ks * 4 + g4) ^ (r15 & 7)) << 3)]);
        accO[df] = __builtin_amdgcn_mfma_f32_16x16x32_bf16(pa, vb, accO[df], 0, 0, 0);
      }
    }
    __builtin_amdgcn_s_setprio(0);

    __syncthreads();
  }

  float rl[4];
#pragma unroll
  for (int r = 0; r < 4; ++r) {
    float l = __shfl(accO[4][r], lane & 48, 64);  // sum lives at r15==0 of accO[4]
    rl[r] = 1.f / l;
  }
#pragma unroll
  for (int df = 0; df < 4; ++df)
#pragma unroll
    for (int r = 0; r < 4; ++r) {
      float o = accO[df][r] * rl[r];
      Oh[((size_t)bh * SS + q0 + wave * 16 + g4 * 4 + r) * 64 + df * 16 + r15] = f2b(o);
    }
}

extern "C" void kernel_launch(void* const* d_in, const int* in_sizes, int n_in,
                              void* d_out, int out_size, void* d_ws, size_t ws_size,
                              hipStream_t stream) {
  const float* query = (const float*)d_in[0];
  const float* key = (const float*)d_in[1];
  const float* value = (const float*)d_in[2];
  const float* pe = (const float*)d_in[3];
  const float* pp = (const float*)d_in[4];
  const float* cpe = (const float*)d_in[5];
  const float* cpp = (const float*)d_in[6];
  const float* relq = (const float*)d_in[7];
  const float* relk = (const float*)d_in[8];
  const float* relv = (const float*)d_in[9];
  const float* Wq = (const float*)d_in[10];
  const float* Wk = (const float*)d_in[11];
  const float* Wv = (const float*)d_in[12];
  const float* Wo = (const float*)d_in[13];
  float* out = (float*)d_out;
  char* ws = (char*)d_ws;

  unsigned short* Xq = (unsigned short*)(ws + 0);
  unsigned short* Xk = (unsigned short*)(ws + 8388608);
  unsigned short* Xv = (unsigned short*)(ws + 16777216);
  unsigned short* Wqb = (unsigned short*)(ws + 25165824);
  unsigned short* Wkb = (unsigned short*)(ws + 27262976);
  unsigned short* Wvb = (unsigned short*)(ws + 29360128);
  unsigned short* Wob = (unsigned short*)(ws + 31457280);
  unsigned short* Qt = (unsigned short*)(ws + 33554432);
  unsigned short* Kt = (unsigned short*)(ws + 54525952);
  unsigned short* Vp = (unsigned short*)(ws + 75497472);
  unsigned short* Oh = (unsigned short*)(ws + 0);         // alias Xq (dead after proj)
  unsigned short* VpT = (unsigned short*)(ws + 8388608);  // alias Xk+Xv (dead after proj), 10.5MB

  convert7<<<dim3(1024, 7, 1), 256, 0, stream>>>(query, key, value, Wq, Wk, Wv, Wo, Xq, Xk, Xv,
                                                 Wqb, Wkb, Wvb, Wob);
  proj_qkv<<<dim3(32, 8, 3), 256, 0, stream>>>(Xq, Xk, Xv, Wqb, Wkb, Wvb, Qt, Kt, Vp);
  aug_dots_mfma2<<<dim3(8, 64, 2), 256, 0, stream>>>(Qt, Kt, relk, relq);
  pos_copy2<<<dim3(16, 64, 2), 256, 0, stream>>>(Qt, Kt, cpe, cpp, pe, pp);
  vprime_T<<<dim3(16, 64, 1), 256, 0, stream>>>(Vp, pe, pp, relv, VpT);
  flash_attn3<<<dim3(8, 64, 1), 512, 0, stream>>>(Qt, Kt, VpT, Oh);
  gemm_out<<<dim3(32, 8, 1), 256, 0, stream>>>(Oh, Wob, out);
}